// Round 2
// baseline (600.818 us; speedup 1.0000x reference)
//
#include <hip/hip_runtime.h>

// Problem constants (match reference)
#define NUM_CHIPS 8
#define EPC 8
#define E_EXPERTS 64
#define TOPK 4
#define META 8
#define M_CAP 1024
#define SEQ 512
#define HID 2048
#define SK (SEQ * TOPK)          // 2048 dispatch entries per chip
#define ROWS (E_EXPERTS * M_CAP) // 65536 output rows

// d_out layout (flat float32):
//   dispatched : [0, ROWS*HID)
//   metadata   : [ROWS*HID, ROWS*HID + ROWS*META)
//   tokens     : [ROWS*HID + ROWS*META, +64)
#define DISP_SZ ((size_t)ROWS * HID)           // 134217728
#define META_OFF DISP_SZ
#define TOK_OFF (DISP_SZ + (size_t)ROWS * META)

// d_ws layout (ints)
#define WS_INV 0                    // inv_map[65536]: entry id per used slot
#define WS_CNT (ROWS)               // counts[8][64]
#define WS_OFB (ROWS + 512)         // offset_base[8][64]
#define WS_TOT (ROWS + 1024)        // total[64]

// Native 4-float vector usable with __builtin_nontemporal_store
typedef float vfloat4 __attribute__((ext_vector_type(4)));

// ---------------------------------------------------------------------------
// Kernel 1: per-chip expert histogram. One block per chip, 256 threads
// (4 segments x 64 experts). Indices staged as bytes in LDS; scan reads are
// wave-uniform words (broadcast, conflict-free).
// ---------------------------------------------------------------------------
__global__ __launch_bounds__(256) void count_kernel(const int* __restrict__ idx,
                                                    int* __restrict__ ws) {
    const int c = blockIdx.x;
    const int t = threadIdx.x;
    __shared__ __align__(16) unsigned char f[SK];
    __shared__ int partial[4][E_EXPERTS];

    const int* ic = idx + c * SK;
    for (int i = t; i < SK; i += 256) f[i] = (unsigned char)ic[i];
    __syncthreads();

    const int e = t & 63;
    const int q = t >> 6;
    const unsigned eb = (unsigned)e;
    const unsigned* fw = (const unsigned*)f;
    int cnt = 0;
    for (int w = q * 128; w < q * 128 + 128; ++w) {
        unsigned v = fw[w];
        cnt += ((v & 0xffu) == eb);
        cnt += (((v >> 8) & 0xffu) == eb);
        cnt += (((v >> 16) & 0xffu) == eb);
        cnt += ((v >> 24) == eb);
    }
    partial[q][e] = cnt;
    __syncthreads();
    if (q == 0) {
        int s = partial[0][e] + partial[1][e] + partial[2][e] + partial[3][e];
        ws[WS_CNT + c * E_EXPERTS + e] = s;
    }
}

// ---------------------------------------------------------------------------
// Kernel 2: exclusive prefix over chips -> offset_base; totals; writes
// tokens_per_expert output (as float). 1 block, 64 threads.
// ---------------------------------------------------------------------------
__global__ void prefix_kernel(int* __restrict__ ws, float* __restrict__ out) {
    const int e = threadIdx.x;  // 0..63
    int base = 0;
    for (int c = 0; c < NUM_CHIPS; ++c) {
        ws[WS_OFB + c * E_EXPERTS + e] = base;
        base += ws[WS_CNT + c * E_EXPERTS + e];
    }
    ws[WS_TOT + e] = base;
    out[TOK_OFF + e] = (float)base;
}

// ---------------------------------------------------------------------------
// Kernel 3: per-entry rank + scatter entry ids into inv_map. One block per
// chip. Slots per expert are dense [0,total_e) so inv_map needs no init.
// ---------------------------------------------------------------------------
__global__ __launch_bounds__(256) void rank_kernel(const int* __restrict__ idx,
                                                   int* __restrict__ ws) {
    const int c = blockIdx.x;
    const int t = threadIdx.x;
    __shared__ __align__(16) unsigned char f[SK];
    __shared__ int partial[4][E_EXPERTS];

    const int* ic = idx + c * SK;
    for (int i = t; i < SK; i += 256) f[i] = (unsigned char)ic[i];
    __syncthreads();

    const int e = t & 63;
    const int q = t >> 6;
    const unsigned eb = (unsigned)e;
    const unsigned* fw = (const unsigned*)f;
    int cnt = 0;
    for (int w = q * 128; w < q * 128 + 128; ++w) {
        unsigned v = fw[w];
        cnt += ((v & 0xffu) == eb);
        cnt += (((v >> 8) & 0xffu) == eb);
        cnt += (((v >> 16) & 0xffu) == eb);
        cnt += ((v >> 24) == eb);
    }
    partial[q][e] = cnt;
    __syncthreads();

    int base = ws[WS_OFB + c * E_EXPERTS + e];
    for (int qq = 0; qq < q; ++qq) base += partial[qq][e];

    int* inv = ws + WS_INV;
    for (int i = q * 512; i < q * 512 + 512; ++i) {
        if ((int)f[i] == e) {
            inv[e * M_CAP + base] = c * SK + i;  // entry id
            ++base;
        }
    }
}

// ---------------------------------------------------------------------------
// Kernel 4: the 512 MB writer. One block per output row (65536 blocks).
// Used rows (p < total[e]): copy token hidden state + metadata.
// Unused rows: zeros + metadata = -1. Non-temporal stores (no write reuse).
// ---------------------------------------------------------------------------
__global__ __launch_bounds__(256) void fill_kernel(const float* __restrict__ x,
                                                   const float* __restrict__ wts,
                                                   const int* __restrict__ ws,
                                                   float* __restrict__ out) {
    const int row = blockIdx.x;
    const int e = row >> 10;         // expert
    const int p = row & (M_CAP - 1); // position within expert buffer
    const int t = threadIdx.x;

    const int total = ws[WS_TOT + e];
    vfloat4* d4 = (vfloat4*)(out + (size_t)row * HID);
    float* meta = out + META_OFF + (size_t)row * META;

    if (p < total) {
        const int entry = ws[WS_INV + row];
        const int c = entry >> 11;        // entry / 2048
        const int i = entry & (SK - 1);   // entry % 2048
        const int tok = i >> 2;
        const int k = i & 3;
        const vfloat4* s4 = (const vfloat4*)(x + ((size_t)(c * SEQ + tok)) * HID);
        vfloat4 v0 = s4[t];
        vfloat4 v1 = s4[t + 256];
        __builtin_nontemporal_store(v0, d4 + t);
        __builtin_nontemporal_store(v1, d4 + t + 256);
        if (t < META) {
            float mv;
            if (t == 0)      mv = (float)c;
            else if (t == 1) mv = (float)tok;
            else if (t == 2) mv = (float)k;
            else if (t == 3) mv = (float)e;
            else if (t == 4) mv = (float)((int)wts[(c * SEQ + tok) * TOPK + k]);
            else             mv = 0.0f;
            meta[t] = mv;
        }
    } else {
        vfloat4 z = (vfloat4)(0.0f);
        __builtin_nontemporal_store(z, d4 + t);
        __builtin_nontemporal_store(z, d4 + t + 256);
        if (t < META) meta[t] = -1.0f;
    }
}

// ---------------------------------------------------------------------------
extern "C" void kernel_launch(void* const* d_in, const int* in_sizes, int n_in,
                              void* d_out, int out_size, void* d_ws, size_t ws_size,
                              hipStream_t stream) {
    const float* x   = (const float*)d_in[0];   // (8,512,2048) f32
    const float* wts = (const float*)d_in[1];   // (8,512,4) f32
    const int* idx   = (const int*)d_in[2];     // (8,512,4) i32
    float* out = (float*)d_out;
    int* ws = (int*)d_ws;

    count_kernel<<<NUM_CHIPS, 256, 0, stream>>>(idx, ws);
    prefix_kernel<<<1, 64, 0, stream>>>(ws, out);
    rank_kernel<<<NUM_CHIPS, 256, 0, stream>>>(idx, ws);
    fill_kernel<<<ROWS, 256, 0, stream>>>(x, wts, ws, out);
}